// Round 5
// baseline (116.238 us; speedup 1.0000x reference)
//
#include <hip/hip_runtime.h>
#include <hip/hip_bf16.h>
#include <math.h>

// MultiHeadAttentionQuantum, B=2048 S=1 E=1024 H=128 DK=NW=8
// All inputs/outputs float32.
//
// Algebra: S==1 -> attention out == v = x @ Wv^T (wq,wk dead).
// RX compose additively; CNOTs are XOR basis permutations ->
//   t_j = cos(v_j + rx_j);  qout[0]=t1*...*t7;  qout[w>=1]=t0*...*tw
// out = qout @ Wc^T + bc
//
// R4 post-mortem: 1 block/CU (grid 256) = 1 wave/SIMD, VGPR-roundtrip staging,
// 2 barriers/iter -> ~35-40 us/GEMM. R5: m97 structure at 64x64 tiles:
// global_load_lds width-16 into FRAGMENT-ORDERED LDS (lane l frag at l*16B:
// async-copy layout == MFMA layout, ds_read_b128 conflict-free), BK=64,
// single-barrier double-buffered K-loop, 512 blocks = 2 blocks/CU.

#define BB 2048
#define EN 1024

typedef short s16x8 __attribute__((ext_vector_type(8)));
typedef float f32x4 __attribute__((ext_vector_type(4)));

union Frag { s16x8 v; __hip_bfloat16 h[8]; };

__device__ inline s16x8 cvt_frag(f32x4 lo, f32x4 hi) {
    Frag u;
    #pragma unroll
    for (int j = 0; j < 4; ++j) {
        u.h[j]     = __float2bfloat16(lo[j]);
        u.h[4 + j] = __float2bfloat16(hi[j]);
    }
    return u.v;
}

// async 16B global -> LDS (lds base must be wave-uniform; HW adds lane*16)
__device__ inline void gll16(const __hip_bfloat16* g, __hip_bfloat16* l) {
    __builtin_amdgcn_global_load_lds(
        (const __attribute__((address_space(1))) void*)g,
        (__attribute__((address_space(3))) void*)l,
        16, 0, 0);
}

// Convert x (nx groups of 8), wv, wc (131072 groups each) -> bf16.
__global__ __launch_bounds__(256) void cvt3_kernel(
        const float* __restrict__ x, const float* __restrict__ wv,
        const float* __restrict__ wc,
        __hip_bfloat16* __restrict__ xb, __hip_bfloat16* __restrict__ wvb,
        __hip_bfloat16* __restrict__ wcb, int nx)
{
    const int g = blockIdx.x * 256 + threadIdx.x;
    const int NG = (EN * EN) / 8;                  // 131072
    const float* s; __hip_bfloat16* d; size_t off;
    if (g < nx)           { s = x;  d = xb;  off = (size_t)g * 8; }
    else if (g < nx + NG) { s = wv; d = wvb; off = (size_t)(g - nx) * 8; }
    else                  { s = wc; d = wcb; off = (size_t)(g - nx - NG) * 8; }
    f32x4 lo = *(const f32x4*)(s + off);
    f32x4 hi = *(const f32x4*)(s + off + 4);
    *(s16x8*)(d + off) = cvt_frag(lo, hi);
}

// GEMM: C[m,n] = sum_k A[m,k] * W[n,k].  A: 2048xEN, W: ENxEN, both bf16
// K-contiguous. Tile 64x64, BK=64, 256 thr (4 waves, 2x2), wave tile 32x32.
//
// LDS (32 KB, double-buffered): per buffer [A: 8 frag-tiles][B: 8 frag-tiles],
// frag-tile = 1024 B = 16(rows)x32(k): lane l holds row l&15, k (l>>4)*8..+8
// at tile_base + l*16B == exactly the mfma_f32_16x16x32_bf16 A/B fragment.
// A tile (mt,kt) at elem (mt*2+kt)*512; B tile (nt,kt) at 4096+(nt*2+kt)*512.
//
// EPI 0: store bf16. EPI 1: store f32 + bias.
template <int EPI>
__global__ __launch_bounds__(256, 2) void gemm_kernel(
        const __hip_bfloat16* __restrict__ A,
        const __hip_bfloat16* __restrict__ W,
        const float* __restrict__ bias,
        void* __restrict__ Cv)
{
    __shared__ __hip_bfloat16 lds[16384];   // 2 buffers x 8192 elems (16 KB)

    const int tid  = threadIdx.x;
    const int wave = tid >> 6, lane = tid & 63;
    const int l15 = lane & 15, lq = lane >> 4;
    const int m0 = blockIdx.x * 64, n0 = blockIdx.y * 64;
    const int wm = (wave & 1) * 32, wn = (wave >> 1) * 32;

    // staging: wave stages 4 of the 16 tiles: t = wave*4+i
    // t<8: A tile mt=t>>1, kt=t&1 ; t>=8: B tile nt=(t-8)>>1, kt=t&1
    const __hip_bfloat16* gsrc[4];
    int ldst[4];
    #pragma unroll
    for (int i = 0; i < 4; ++i) {
        const int t  = wave * 4 + i;
        const int kt = t & 1;
        int row, lofs;
        const __hip_bfloat16* base;
        if (t < 8) { const int mt = t >> 1;       row = m0 + mt * 16 + l15; base = A; lofs = t * 512; }
        else       { const int nt = (t - 8) >> 1; row = n0 + nt * 16 + l15; base = W; lofs = 4096 + (t - 8) * 512; }
        gsrc[i] = base + (size_t)row * EN + kt * 32 + lq * 8;
        ldst[i] = lofs;
    }

    f32x4 acc[2][2] = {};

    // single-barrier double-buffered K-loop (16 iters of BK=64)
    #pragma unroll
    for (int i = 0; i < 4; ++i) gll16(gsrc[i], &lds[ldst[i]]);
    __syncthreads();

    int p = 0;
    for (int k0 = 64; k0 <= EN; k0 += 64) {
        if (k0 < EN) {
            const int q = p ^ 1;
            #pragma unroll
            for (int i = 0; i < 4; ++i) gll16(gsrc[i] + k0, &lds[q * 8192 + ldst[i]]);
        }
        const __hip_bfloat16* Ab = &lds[p * 8192];
        const __hip_bfloat16* Bb = Ab + 4096;
        #pragma unroll
        for (int kt = 0; kt < 2; ++kt) {
            s16x8 a[2], b[2];
            #pragma unroll
            for (int mi = 0; mi < 2; ++mi)
                a[mi] = *(const s16x8*)&Ab[((wm >> 4) + mi) * 1024 + kt * 512 + lane * 8];
            #pragma unroll
            for (int nj = 0; nj < 2; ++nj)
                b[nj] = *(const s16x8*)&Bb[((wn >> 4) + nj) * 1024 + kt * 512 + lane * 8];
            #pragma unroll
            for (int mi = 0; mi < 2; ++mi)
                #pragma unroll
                for (int nj = 0; nj < 2; ++nj)
                    acc[mi][nj] = __builtin_amdgcn_mfma_f32_16x16x32_bf16(
                                      a[mi], b[nj], acc[mi][nj], 0, 0, 0);
        }
        __syncthreads();   // drains vmcnt -> next buffer ready; reads of p done
        p ^= 1;
    }

    if (EPI == 0) {
        __hip_bfloat16* C = (__hip_bfloat16*)Cv;
        #pragma unroll
        for (int mi = 0; mi < 2; ++mi)
            #pragma unroll
            for (int nj = 0; nj < 2; ++nj) {
                const int col = n0 + wn + nj * 16 + l15;
                #pragma unroll
                for (int r = 0; r < 4; ++r) {
                    const int row = m0 + wm + mi * 16 + lq * 4 + r;
                    C[(size_t)row * EN + col] = __float2bfloat16(acc[mi][nj][r]);
                }
            }
    } else {
        float* C = (float*)Cv;
        #pragma unroll
        for (int nj = 0; nj < 2; ++nj) {
            const int col = n0 + wn + nj * 16 + l15;
            const float bv = bias[col];
            #pragma unroll
            for (int mi = 0; mi < 2; ++mi)
                #pragma unroll
                for (int r = 0; r < 4; ++r) {
                    const int row = m0 + wm + mi * 16 + lq * 4 + r;
                    C[(size_t)row * EN + col] = acc[mi][nj][r] + bv;
                }
        }
    }
}

// One thread per (b,h) group of 8 angles; in-place on V (bf16).
__global__ __launch_bounds__(256) void quantum_kernel(
        __hip_bfloat16* __restrict__ V, const float* __restrict__ rx)
{
    const int g = blockIdx.x * 256 + threadIdx.x;   // exact grid: BB*EN/8
    Frag in;
    in.v = *(const s16x8*)(V + (size_t)g * 8);
    float t[8];
    #pragma unroll
    for (int j = 0; j < 8; ++j)
        t[j] = cosf(__bfloat162float(in.h[j]) + rx[j]);

    Frag o;
    float suf = t[1];
    #pragma unroll
    for (int j = 2; j < 8; ++j) suf *= t[j];
    o.h[0] = __float2bfloat16(suf);
    float p = t[0];
    #pragma unroll
    for (int j = 1; j < 8; ++j) { p *= t[j]; o.h[j] = __float2bfloat16(p); }

    *(s16x8*)(V + (size_t)g * 8) = o.v;
}

extern "C" void kernel_launch(void* const* d_in, const int* in_sizes, int n_in,
                              void* d_out, int out_size, void* d_ws, size_t ws_size,
                              hipStream_t stream)
{
    // inputs: x, wq, wk, wv, wc, bc, rx_params (wq/wk dead: S==1)
    const float* x  = (const float*)d_in[0];
    const float* wv = (const float*)d_in[3];
    const float* wc = (const float*)d_in[4];
    const float* bc = (const float*)d_in[5];
    const float* rx = (const float*)d_in[6];
    float* out = (float*)d_out;

    const size_t XE = (size_t)BB * EN;   // 2M elems
    const size_t WE = (size_t)EN * EN;   // 1M elems

    // ws layout (12 MB; harness provides ~268 MB): [xb 4MB|wvb 2MB|wcb 2MB|V 4MB]
    __hip_bfloat16* xb  = (__hip_bfloat16*)d_ws;
    __hip_bfloat16* wvb = xb + XE;
    __hip_bfloat16* wcb = wvb + WE;
    __hip_bfloat16* V   = wcb + WE;

    dim3 grid(BB / 64, EN / 64);         // 32 x 16 = 512 blocks
    cvt3_kernel<<<(int)((XE / 8 + 2 * (WE / 8)) / 256), 256, 0, stream>>>(
        x, wv, wc, xb, wvb, wcb, (int)(XE / 8));
    gemm_kernel<0><<<grid, 256, 0, stream>>>(xb, wvb, nullptr, V);
    quantum_kernel<<<(int)(XE / 8 / 256), 256, 0, stream>>>(V, rx);
    gemm_kernel<1><<<grid, 256, 0, stream>>>(V, wcb, bc, out);
}